// Round 8
// baseline (1004.437 us; speedup 1.0000x reference)
//
#include <hip/hip_runtime.h>
#include <hip/hip_bf16.h>
#include <cmath>

#define B_ 2
#define L_ 1024
#define DM 1024
#define DI 2048
#define NS 16
#define RR 64
#define KC 4
#define NCH 64
#define CL (L_ / NCH)   // 16
#define NSPLIT 8        // dbl GEMM split-K factor

#define VMCNT(N) asm volatile("s_waitcnt vmcnt(" #N ")" ::: "memory")

using frag8 = __attribute__((ext_vector_type(8))) short;   // 8 bf16 (4 VGPRs)
using facc4 = __attribute__((ext_vector_type(4))) float;   // MFMA C/D
using f32x4 = __attribute__((ext_vector_type(4))) float;

struct alignas(8) S4v { short x, y, z, w; };

__device__ __forceinline__ short f2b(float v) {
    __hip_bfloat16 h = __float2bfloat16(v);
    return *(short*)&h;
}

__device__ __forceinline__ float silu1(float x) {
    return x / (1.f + __expf(-x));
}

// ---- LDS granule swizzle (16-B granules within a 1024-B 16-row group) ----
__device__ __forceinline__ int swz(int r, int q) {
    return (r * 4 + (q ^ (r & 3))) ^ (((r >> 2) & 1) << 2);
}
__device__ __forceinline__ void swz_src(int l, int& R, int& C) {
    int rho = l >> 2;
    R = rho ^ ((rho >> 2) & 1);
    C = (l & 3) ^ (R & 3);
}

// pw vectors: p0 = q^(1..4), p1 = q^(5..8), p2 = q^(9..12), p3 = q^(13..16)
__device__ __forceinline__ void pow4(float qv, f32x4& p0, f32x4& p1, f32x4& p2, f32x4& p3) {
    float q2 = qv * qv, q3 = q2 * qv, q4 = q2 * q2;
    p0 = (f32x4){qv, q2, q3, q4};
    f32x4 s4 = {q4, q4, q4, q4};
    p1 = p0 * s4;
    f32x4 s8 = s4 * s4;
    p2 = p0 * s8;
    p3 = p1 * s8;
}

// async global->LDS DMA, 16 B per lane. LDS dest is wave-uniform base + lane*16.
__device__ __forceinline__ void async_ld16(const void* g, void* l) {
    __builtin_amdgcn_global_load_lds(
        (const __attribute__((address_space(1))) unsigned int*)g,
        (__attribute__((address_space(3))) unsigned int*)l, 16, 0, 0);
}

__device__ __forceinline__ void cvt4(const float* __restrict__ src, size_t si,
                                     short* __restrict__ dst, size_t di2) {
    float4 v = *(const float4*)(src + si);
    S4v r = { f2b(v.x), f2b(v.y), f2b(v.z), f2b(v.w) };
    *(S4v*)(dst + di2) = r;
}

// ---- one launch converting ALL fp32 inputs to bf16 + Av0/structured sidecar ----
__global__ void cvt_all(const float* __restrict__ a, const float* __restrict__ b,
                        const float* __restrict__ Wi,
                        const float* __restrict__ Wx, const float* __restrict__ Wxb2,
                        const float* __restrict__ Wdt, const float* __restrict__ Wdtb2,
                        const float* __restrict__ Wo,
                        const float* __restrict__ Alf, const float* __restrict__ Alb,
                        short* __restrict__ abf, short* __restrict__ bbf,
                        short* __restrict__ Wibf,
                        short* __restrict__ Wxbf, short* __restrict__ Wxbbf,
                        short* __restrict__ Wdtbf, short* __restrict__ Wdtbbf,
                        short* __restrict__ Wobf,
                        float* __restrict__ Av0S, float* __restrict__ stS) {
    size_t i = ((size_t)blockIdx.x * 256 + threadIdx.x) * 4;
    const size_t S_ab = (size_t)B_ * L_ * DM;
    if (i < S_ab) { cvt4(a, i, abf, i); return; } i -= S_ab;
    if (i < S_ab) {                      // b, flipped along L
        size_t r = i / DM, c = i % DM;
        size_t bb = r / L_, ll = r % L_;
        size_t sr = bb * L_ + (L_ - 1 - ll);
        cvt4(b, sr * DM + c, bbf, i); return;
    } i -= S_ab;
    const size_t S_wi = (size_t)2 * DI * DM;
    if (i < S_wi) { cvt4(Wi, i, Wibf, i); return; } i -= S_wi;
    const size_t S_wx = (size_t)96 * DI;
    if (i < S_wx) { cvt4(Wx, i, Wxbf, i); return; } i -= S_wx;
    if (i < S_wx) { cvt4(Wxb2, i, Wxbbf, i); return; } i -= S_wx;
    const size_t S_wd = (size_t)DI * RR;
    if (i < S_wd) { cvt4(Wdt, i, Wdtbf, i); return; } i -= S_wd;
    if (i < S_wd) { cvt4(Wdtb2, i, Wdtbbf, i); return; } i -= S_wd;
    const size_t S_wo = (size_t)DM * DI;
    if (i < S_wo) { cvt4(Wo, i, Wobf, i); return; } i -= S_wo;
    const size_t S_av = (size_t)2 * DI;  // Av0 + structured flag per (branch, d)
    if (i < S_av) {
#pragma unroll
        for (int k2 = 0; k2 < 4; ++k2) {
            size_t idx = i + k2;
            int br2 = (int)(idx / DI), d2 = (int)(idx % DI);
            const float* Al = br2 ? Alb : Alf;
            float Av0 = -__expf(Al[(size_t)d2 * NS]);
            bool st = true;
            for (int n = 1; n < NS; ++n) {
                float Avn = -__expf(Al[(size_t)d2 * NS + n]);
                st = st && (fabsf(Avn - (n + 1) * Av0) <= 1e-4f * (n + 1) * fabsf(Av0));
            }
            Av0S[idx] = Av0;
            stS[idx] = st ? 1.f : 0.f;
        }
    }
}

// ---- shared MFMA GEMM body: depth-2 pipelined (3 LDS bufs, counted vmcnt) ----
template <int BM>
__device__ __forceinline__ void gemm_body(
    const short* A, int lda, const short* W, int ldw, int wRowOff,
    float* C, int ldc, int K, int m0, int n0) {
    constexpr int MF = BM / 32;
    __shared__ __align__(16) short As[3][BM * 32];
    __shared__ __align__(16) short Ws[3][64 * 32];
    const int tid = threadIdx.x;
    const int lane = tid & 63, wv = tid >> 6;
    const int wm = (wv & 1) * (BM / 2), wn = (wv >> 1) * 32;
    const int q = lane >> 4, mr = lane & 15;
    int sR, sC; swz_src(lane, sR, sC);
    const int sg = swz(mr, q) * 8;

    const short* Ag = A + (size_t)(m0 + wv * 16 + sR) * lda + sC * 8;
    const short* Wg = W + (size_t)(n0 + wRowOff + wv * 16 + sR) * ldw + sC * 8;

    facc4 acc[MF][2];
#pragma unroll
    for (int i = 0; i < MF; ++i)
#pragma unroll
        for (int j = 0; j < 2; ++j) acc[i][j] = (facc4){0.f, 0.f, 0.f, 0.f};

    auto stage = [&](int ks, int b) {
        int k0 = ks * 32;
        async_ld16(Ag + k0, &As[b][wv * 512]);
        if constexpr (BM == 128)
            async_ld16(Ag + (size_t)64 * lda + k0, &As[b][wv * 512 + 2048]);
        async_ld16(Wg + k0, &Ws[b][wv * 512]);
    };

    const int nk = K / 32;
    stage(0, 0);
    if (nk > 1) stage(1, 1);
    int buf = 0;
    for (int it = 0; it < nk; ++it) {
        if (it == nk - 1) VMCNT(0);
        else if (BM == 128) VMCNT(3);
        else VMCNT(2);
        __builtin_amdgcn_s_barrier();
        asm volatile("" ::: "memory");
        if (it + 2 < nk) { int b2 = buf + 2; if (b2 >= 3) b2 -= 3; stage(it + 2, b2); }
        frag8 af[MF], wf[2];
#pragma unroll
        for (int t = 0; t < MF; ++t)
            af[t] = *(const frag8*)&As[buf][(wm + t * 16) * 32 + sg];
#pragma unroll
        for (int j = 0; j < 2; ++j)
            wf[j] = *(const frag8*)&Ws[buf][(wn + j * 16) * 32 + sg];
#pragma unroll
        for (int i = 0; i < MF; ++i)
#pragma unroll
            for (int j = 0; j < 2; ++j)
                acc[i][j] = __builtin_amdgcn_mfma_f32_16x16x32_bf16(af[i], wf[j], acc[i][j], 0, 0, 0);
        buf = (buf == 2) ? 0 : buf + 1;
    }
#pragma unroll
    for (int i = 0; i < MF; ++i)
#pragma unroll
        for (int j = 0; j < 2; ++j) {
            int gn = n0 + wn + j * 16 + mr;
#pragma unroll
            for (int e = 0; e < 4; ++e) {
                int gm = m0 + wm + i * 16 + q * 4 + e;
                C[(size_t)gm * ldc + gn] = acc[i][j][e];
            }
        }
}

// ---- fused xz GEMM + depthwise causal conv(K=4) + SiLU (R6-best 2-buffer form) ----
// bz=0: x_f AND z share the staged A tile (16 MFMA/wave/iter); bz=1: x_b.
__global__ __launch_bounds__(256) void gemm_xz_conv(
    const short* __restrict__ abf, const short* __restrict__ bbf,
    const short* __restrict__ Wibf,
    float* __restrict__ UF, float* __restrict__ UB, float* __restrict__ Z,
    short* __restrict__ CFo, short* __restrict__ CBo,
    const float* __restrict__ cwf, const float* __restrict__ cbf2,
    const float* __restrict__ cwb, const float* __restrict__ cbb2) {
    __shared__ __align__(16) char smem[34816];
    short (*As)[4608]  = (short (*)[4608])smem;             // [2][128*32 + 16*32 halo]
    short (*Wsx)[2048] = (short (*)[2048])(smem + 18432);   // [2][64*32]
    short (*Wsz)[2048] = (short (*)[2048])(smem + 26624);   // [2][64*32]
    float (*Xs)[68] = (float (*)[68])smem;                  // [80][68] overlay

    const int bz = blockIdx.z;
    const bool hasZ = (bz == 0);
    const int tid = threadIdx.x;
    const int lane = tid & 63, wv = tid >> 6;
    const int id = blockIdx.y * gridDim.x + blockIdx.x;   // 0..511
    const int xcd = id & 7, idx = id >> 3;
    const int nt = (xcd & 3) * 8 + (idx & 7);             // n-tile 0..31
    const int mt = (xcd >> 2) * 8 + (idx >> 3);           // m-tile 0..15
    const int m0 = mt * 128, n0 = nt * 64;
    const bool hasHalo = (m0 % L_ != 0);
    const int wm = (wv & 1) * 64, wn = (wv >> 1) * 32;
    const int q = lane >> 4, mr = lane & 15;
    int sR, sC; swz_src(lane, sR, sC);
    const int sg = swz(mr, q) * 8;

    const short* A = bz ? bbf : abf;

    const short* Ag  = A + (size_t)(m0 + wv * 16 + sR) * DM + sC * 8;
    const short* Agh = A + (size_t)(m0 - 16 + sR) * DM + sC * 8;
    const short* Wgx = Wibf + (size_t)(n0 + wv * 16 + sR) * DM + sC * 8;
    const short* Wgz = Wibf + (size_t)(n0 + DI + wv * 16 + sR) * DM + sC * 8;

    facc4 accx[4][2], accz[4][2], hacc[2];
#pragma unroll
    for (int i = 0; i < 4; ++i)
#pragma unroll
        for (int j = 0; j < 2; ++j) {
            accx[i][j] = (facc4){0.f, 0.f, 0.f, 0.f};
            accz[i][j] = (facc4){0.f, 0.f, 0.f, 0.f};
        }
#pragma unroll
    for (int j = 0; j < 2; ++j) hacc[j] = (facc4){0.f, 0.f, 0.f, 0.f};

    async_ld16(Ag, &As[0][wv * 512]);
    async_ld16(Ag + (size_t)64 * DM, &As[0][wv * 512 + 2048]);
    async_ld16(Wgx, &Wsx[0][wv * 512]);
    if (hasZ) async_ld16(Wgz, &Wsz[0][wv * 512]);
    if (hasHalo && wv == 0) async_ld16(Agh, &As[0][4096]);

    const int nk = DM / 32;
    for (int it = 0; it < nk; ++it) {
        const int buf = it & 1;
        __syncthreads();
        if (it + 1 < nk) {
            int k0 = (it + 1) * 32;
            async_ld16(Ag + k0, &As[buf ^ 1][wv * 512]);
            async_ld16(Ag + (size_t)64 * DM + k0, &As[buf ^ 1][wv * 512 + 2048]);
            async_ld16(Wgx + k0, &Wsx[buf ^ 1][wv * 512]);
            if (hasZ) async_ld16(Wgz + k0, &Wsz[buf ^ 1][wv * 512]);
            if (hasHalo && wv == 0) async_ld16(Agh + k0, &As[buf ^ 1][4096]);
        }
        frag8 af[4], wfx[2], wfz[2];
#pragma unroll
        for (int t = 0; t < 4; ++t)
            af[t] = *(const frag8*)&As[buf][(wm + t * 16) * 32 + sg];
#pragma unroll
        for (int j = 0; j < 2; ++j)
            wfx[j] = *(const frag8*)&Wsx[buf][(wn + j * 16) * 32 + sg];
        if (hasZ) {
#pragma unroll
            for (int j = 0; j < 2; ++j)
                wfz[j] = *(const frag8*)&Wsz[buf][(wn + j * 16) * 32 + sg];
        }
        if (hasHalo && wm == 0) {
            frag8 afh = *(const frag8*)&As[buf][4096 + sg];
#pragma unroll
            for (int j = 0; j < 2; ++j)
                hacc[j] = __builtin_amdgcn_mfma_f32_16x16x32_bf16(afh, wfx[j], hacc[j], 0, 0, 0);
        }
#pragma unroll
        for (int i = 0; i < 4; ++i)
#pragma unroll
            for (int j = 0; j < 2; ++j)
                accx[i][j] = __builtin_amdgcn_mfma_f32_16x16x32_bf16(af[i], wfx[j], accx[i][j], 0, 0, 0);
        if (hasZ) {
#pragma unroll
            for (int i = 0; i < 4; ++i)
#pragma unroll
                for (int j = 0; j < 2; ++j)
                    accz[i][j] = __builtin_amdgcn_mfma_f32_16x16x32_bf16(af[i], wfz[j], accz[i][j], 0, 0, 0);
        }
    }

    if (hasZ) {
#pragma unroll
        for (int i = 0; i < 4; ++i)
#pragma unroll
            for (int j = 0; j < 2; ++j) {
                int gn = n0 + wn + j * 16 + mr;
#pragma unroll
                for (int e = 0; e < 4; ++e) {
                    int gm = m0 + wm + i * 16 + q * 4 + e;
                    Z[(size_t)gm * DI + gn] = accz[i][j][e];
                }
            }
    }

    const float* cw = bz ? cwb : cwf;
    const float* cb = bz ? cbb2 : cbf2;
    float* U   = bz ? UB : UF;
    short* Co  = bz ? CBo : CFo;
    const int col = tid & 63;
    const int dcol = n0 + col;
    const int rg = tid >> 6;
    float4 wd = *(const float4*)(cw + (size_t)dcol * KC);
    float bd = cb[dcol];

    __syncthreads();    // all As/Ws reads done before overlay
#pragma unroll
    for (int p = 0; p < 2; ++p) {
        if (p == 0) {
            if ((wv & 1) == 0) {
#pragma unroll
                for (int j = 0; j < 2; ++j) {
#pragma unroll
                    for (int e = 0; e < 4; ++e)
                        Xs[q * 4 + e][wn + j * 16 + mr] = hacc[j][e];
#pragma unroll
                    for (int i = 0; i < 4; ++i)
#pragma unroll
                        for (int e = 0; e < 4; ++e)
                            Xs[16 + i * 16 + q * 4 + e][wn + j * 16 + mr] = accx[i][j][e];
                }
            }
        } else {
            if ((wv & 1) == 0) {
#pragma unroll
                for (int j = 0; j < 2; ++j)
#pragma unroll
                    for (int e = 0; e < 4; ++e)
                        Xs[q * 4 + e][wn + j * 16 + mr] = accx[3][j][e];
            } else {
#pragma unroll
                for (int j = 0; j < 2; ++j)
#pragma unroll
                    for (int i = 0; i < 4; ++i)
#pragma unroll
                        for (int e = 0; e < 4; ++e)
                            Xs[16 + i * 16 + q * 4 + e][wn + j * 16 + mr] = accx[i][j][e];
            }
        }
        __syncthreads();
#pragma unroll
        for (int rr = 0; rr < 16; ++rr) {
            int rl = rg * 16 + rr;
            float x0 = Xs[13 + rl][col];
            float x1 = Xs[14 + rl][col];
            float x2 = Xs[15 + rl][col];
            float x3 = Xs[16 + rl][col];
            float v = bd + x0 * wd.x + x1 * wd.y + x2 * wd.z + x3 * wd.w;
            float s2 = silu1(v);
            size_t go = (size_t)(m0 + p * 64 + rl) * DI + dcol;
            U[go] = s2;
            Co[go] = f2b(s2);
        }
        if (p == 0) __syncthreads();
    }
}

// batched dt GEMM: dt[M,DI] = dtraw[M,64] @ Wdt[DI,64]^T, both branches (BM=128)
__global__ __launch_bounds__(256) void gemm_dt(
    const short* __restrict__ dtf, const short* __restrict__ dtb,
    const short* __restrict__ Wf, const short* __restrict__ Wb,
    float* __restrict__ DTF_, float* __restrict__ DTB_) {
    const int bz = blockIdx.z;
    gemm_body<128>(bz ? dtb : dtf, RR, bz ? Wb : Wf, RR, 0,
                   bz ? DTB_ : DTF_, DI, RR, blockIdx.y * 128, blockIdx.x * 64);
}

// final GEMM: out[M,DM] = g[M,DI] @ Wo[DM,DI]^T
__global__ __launch_bounds__(256) void gemm_out(
    const short* __restrict__ gbf, const short* __restrict__ Wobf,
    float* __restrict__ out) {
    gemm_body<64>(gbf, DI, Wobf, DI, 0, out, DM, DI, blockIdx.y * 64, blockIdx.x * 64);
}

// batched dbl GEMM: part[z][M][96] = C{F,B}[M,kchunk] * Wx{f,b}[96,kchunk]^T
__global__ __launch_bounds__(256) void gemm_dbl(
    const short* __restrict__ CF, const short* __restrict__ CB,
    const short* __restrict__ Wxf, const short* __restrict__ Wxb,
    float* __restrict__ part) {
    __shared__ __align__(16) short As[2][128 * 32];
    __shared__ __align__(16) short Ws[2][96 * 32];
    const int br = blockIdx.z / NSPLIT, zz = blockIdx.z % NSPLIT;
    const short* A = br ? CB : CF;
    const short* W = br ? Wxb : Wxf;
    constexpr int Kchunk = DI / NSPLIT;
    const int tid = threadIdx.x;
    const int lane = tid & 63, wv = tid >> 6;
    const int m0 = blockIdx.y * 128;
    const int kOff = zz * Kchunk;
    const int wm = (wv & 1) * 64, wn = (wv >> 1) * 48;
    const int q = lane >> 4, mr = lane & 15;
    int sR, sC; swz_src(lane, sR, sC);
    const int sg = swz(mr, q) * 8;

    const short* Ag = A + (size_t)(m0 + wv * 16 + sR) * DI + sC * 8 + kOff;
    const short* Wg = W + (size_t)(wv * 16 + sR) * DI + sC * 8 + kOff;

    facc4 acc[4][3];
#pragma unroll
    for (int i = 0; i < 4; ++i)
#pragma unroll
        for (int j = 0; j < 3; ++j) acc[i][j] = (facc4){0.f, 0.f, 0.f, 0.f};

    async_ld16(Ag, &As[0][wv * 512]);
    async_ld16(Ag + (size_t)64 * DI, &As[0][wv * 512 + 2048]);
    async_ld16(Wg, &Ws[0][wv * 512]);
    if (wv < 2) async_ld16(Wg + (size_t)64 * DI, &Ws[0][wv * 512 + 2048]);

    const int nk = Kchunk / 32;
    for (int it = 0; it < nk; ++it) {
        const int buf = it & 1;
        __syncthreads();
        if (it + 1 < nk) {
            int k0 = (it + 1) * 32;
            async_ld16(Ag + k0, &As[buf ^ 1][wv * 512]);
            async_ld16(Ag + (size_t)64 * DI + k0, &As[buf ^ 1][wv * 512 + 2048]);
            async_ld16(Wg + k0, &Ws[buf ^ 1][wv * 512]);
            if (wv < 2) async_ld16(Wg + (size_t)64 * DI + k0, &Ws[buf ^ 1][wv * 512 + 2048]);
        }
        frag8 af[4], wf[3];
#pragma unroll
        for (int t = 0; t < 4; ++t)
            af[t] = *(const frag8*)&As[buf][(wm + t * 16) * 32 + sg];
#pragma unroll
        for (int j = 0; j < 3; ++j)
            wf[j] = *(const frag8*)&Ws[buf][(wn + j * 16) * 32 + sg];
#pragma unroll
        for (int i = 0; i < 4; ++i)
#pragma unroll
            for (int j = 0; j < 3; ++j)
                acc[i][j] = __builtin_amdgcn_mfma_f32_16x16x32_bf16(af[i], wf[j], acc[i][j], 0, 0, 0);
    }
    float* Cz = part + (size_t)blockIdx.z * (B_ * L_) * 96;
#pragma unroll
    for (int i = 0; i < 4; ++i)
#pragma unroll
        for (int j = 0; j < 3; ++j) {
            int gn = wn + j * 16 + mr;
#pragma unroll
            for (int e = 0; e < 4; ++e) {
                int gm = m0 + wm + i * 16 + q * 4 + e;
                Cz[(size_t)gm * 96 + gn] = acc[i][j][e];
            }
        }
}

// batched split-K reduce -> dbl fp32 (both branches); cols 0..63 also -> bf16 dt operand
__global__ void reduce_dbl(const float* __restrict__ part,
                           float* __restrict__ dblf, float* __restrict__ dblb,
                           short* __restrict__ dtf, short* __restrict__ dtb) {
    int idx = blockIdx.x * blockDim.x + threadIdx.x;
    const int T = B_ * L_ * 96;
    int br = 0;
    if (idx >= T) { br = 1; idx -= T; }
    const float* p = part + (size_t)br * NSPLIT * T;
    float s = 0.f;
#pragma unroll
    for (int z = 0; z < NSPLIT; ++z) s += p[(size_t)z * T + idx];
    (br ? dblb : dblf)[idx] = s;
    int row = idx / 96, col = idx % 96;
    if (col < RR) (br ? dtb : dtf)[(size_t)row * RR + col] = f2b(s);
}

__device__ __forceinline__ float softplus2(float raw, float bd2) {
    float x = raw + bd2;
    return (x > 20.f) ? x : log1pf(__expf(x));
}

// Pass A (fused local scan), batched over both branches via blockIdx.y = bb + 2*br.
__global__ void scan_chunk(float* UF, float* UB, float* DTFm, float* DTBm,
                           const float* bdtf, const float* bdtb,
                           const float* dblF, const float* dblB,
                           const float* Alf, const float* Alb,
                           const float* Dvf, const float* Dvb,
                           float* SF, float* SB) {
    __shared__ __align__(16) float BCs[CL][32];
    const int tid = threadIdx.x;
    const int d = blockIdx.x * 256 + tid;
    const int br = blockIdx.y >> 1, bb = blockIdx.y & 1;
    const int c = blockIdx.z;
    const int l0 = c * CL;
    float* __restrict__ u = br ? UB : UF;
    float* __restrict__ dtm = br ? DTBm : DTFm;
    const float* __restrict__ bdt = br ? bdtb : bdtf;
    const float* __restrict__ dbl = br ? dblB : dblF;
    const float* __restrict__ A_log = br ? Alb : Alf;
    const float* __restrict__ Dv = br ? Dvb : Dvf;
    float* __restrict__ Sbuf = br ? SB : SF;
    {
        int e = tid * 2;   // CL*32 = 512 floats
        int row = e >> 5, cc = e & 31;
        *(float2*)&BCs[row][cc] =
            *(const float2*)(dbl + ((size_t)(bb * L_ + l0 + row) * 96 + 64 + cc));
    }
    float Av[NS];
#pragma unroll
    for (int n = 0; n < NS; ++n) Av[n] = -__expf(A_log[d * NS + n]);
    bool structured = true;
#pragma unroll
    for (int n = 1; n < NS; ++n)
        structured = structured &&
            (fabsf(Av[n] - (n + 1) * Av[0]) <= 1e-4f * (n + 1) * fabsf(Av[0]));
    const float bd2 = 2.f * bdt[d];
    const float Dd = Dv[d];
    float cd = 0.f;
    __syncthreads();
    float* __restrict__ up = u + ((size_t)bb * L_ + l0) * DI + d;
    float* __restrict__ dp = dtm + ((size_t)bb * L_ + l0) * DI + d;
    size_t pb = ((size_t)(bb * NCH + c) * NS) * DI + d;

    if (structured) {
        const float Av0 = Av[0];
        f32x4 S4[4];
#pragma unroll
        for (int m = 0; m < 4; ++m) S4[m] = (f32x4){0.f, 0.f, 0.f, 0.f};
        float draw = dp[0], ul = up[0];
        for (int l = 0; l < CL; ++l) {
            float draw_n = 0.f, ul_n = 0.f;
            if (l + 1 < CL) { draw_n = dp[(size_t)(l + 1) * DI]; ul_n = up[(size_t)(l + 1) * DI]; }
            float x = draw + bd2;
            float e = __expf(x);
            float del = (x > 20.f) ? x : __logf(1.f + e);
            cd += del;
            float du = del * ul;
            f32x4 pw0, pw1, pw2, pw3;
            pow4(__expf(del * Av0), pw0, pw1, pw2, pw3);
            const f32x4* BC4 = (const f32x4*)&BCs[l][0];
            f32x4 b0 = BC4[0], b1 = BC4[1], b2 = BC4[2], b3 = BC4[3];
            f32x4 c0 = BC4[4], c1 = BC4[5], c2 = BC4[6], c3 = BC4[7];
            f32x4 du4 = {du, du, du, du};
            S4[0] = pw0 * S4[0] + du4 * b0;
            S4[1] = pw1 * S4[1] + du4 * b1;
            S4[2] = pw2 * S4[2] + du4 * b2;
            S4[3] = pw3 * S4[3] + du4 * b3;
            f32x4 pA = S4[0] * c0 + S4[1] * c1;
            f32x4 pB = S4[2] * c2 + S4[3] * c3;
            f32x4 pv = pA + pB;
            float accv = (pv[0] + pv[1]) + (pv[2] + pv[3]);
            dp[(size_t)l * DI] = cd;
            up[(size_t)l * DI] = accv + ul * Dd;
            draw = draw_n; ul = ul_n;
        }
#pragma unroll
        for (int m = 0; m < 4; ++m)
#pragma unroll
            for (int k2 = 0; k2 < 4; ++k2)
                Sbuf[pb + (size_t)(m * 4 + k2) * DI] = S4[m][k2];
    } else {
        float S[NS];
#pragma unroll
        for (int n = 0; n < NS; ++n) S[n] = 0.f;
        float draw = dp[0], ul = up[0];
        for (int l = 0; l < CL; ++l) {
            float draw_n = 0.f, ul_n = 0.f;
            if (l + 1 < CL) { draw_n = dp[(size_t)(l + 1) * DI]; ul_n = up[(size_t)(l + 1) * DI]; }
            float del = softplus2(draw, bd2);
            cd += del;
            float du = del * ul;
            const float* Brow = &BCs[l][0];
            float pa[4] = {0.f, 0.f, 0.f, 0.f};
#pragma unroll
            for (int j = 0; j < 4; ++j)
#pragma unroll
                for (int k = 0; k < 4; ++k) {
                    int n = j * 4 + k;
                    float dA = __expf(del * Av[n]);
                    S[n] = fmaf(dA, S[n], du * Brow[n]);
                    pa[j] = fmaf(S[n], Brow[16 + n], pa[j]);
                }
            float accv = (pa[0] + pa[1]) + (pa[2] + pa[3]);
            dp[(size_t)l * DI] = cd;
            up[(size_t)l * DI] = accv + ul * Dd;
            draw = draw_n; ul = ul_n;
        }
#pragma unroll
        for (int n = 0; n < NS; ++n)
            Sbuf[pb + (size_t)n * DI] = S[n];
    }
}

// Pass B batched: P recomputed as exp(cd_chunk * Av[n]) from the cumulative-delta matrix.
__global__ void scan_combine(float* __restrict__ PF, const float* __restrict__ SF,
                             float* __restrict__ PB, const float* __restrict__ SB,
                             const float* __restrict__ DTFm, const float* __restrict__ DTBm,
                             const float* __restrict__ Alf, const float* __restrict__ Alb) {
    int g = blockIdx.x * blockDim.x + threadIdx.x;
    const int T = B_ * NS * DI;
    int br = (g >= T);
    int gg = br ? g - T : g;
    float* __restrict__ P = br ? PB : PF;
    const float* __restrict__ S = br ? SB : SF;
    const float* __restrict__ cdm = br ? DTBm : DTFm;
    const float* __restrict__ Alog = br ? Alb : Alf;
    int d = gg % DI;
    int rest = gg / DI;
    int n = rest % NS, bb = rest / NS;
    const float Avn = -__expf(Alog[d * NS + n]);
    const size_t stride = (size_t)NS * DI;
    const size_t cstride = (size_t)CL * DI;
    size_t o = ((size_t)(bb * NCH) * NS + n) * DI + d;
    const float* cp = cdm + ((size_t)bb * L_ + CL - 1) * DI + d;
    float h = 0.f;
    float Cc[4], Sc[4], Cn[4], Sn[4];
#pragma unroll
    for (int i = 0; i < 4; ++i) {
        Cc[i] = cp[(size_t)i * cstride];
        Sc[i] = S[o + (size_t)i * stride];
    }
    for (int c = 0; c < NCH; c += 4) {
        if (c + 4 < NCH) {
#pragma unroll
            for (int i = 0; i < 4; ++i) {
                Cn[i] = cp[(size_t)(c + i + 4) * cstride];
                Sn[i] = S[o + (size_t)(i + 4) * stride];
            }
        }
#pragma unroll
        for (int i = 0; i < 4; ++i) {
            P[o] = h;
            h = fmaf(__expf(Cc[i] * Avn), h, Sc[i]);
            o += stride;
        }
#pragma unroll
        for (int i = 0; i < 4; ++i) { Cc[i] = Cn[i]; Sc[i] = Sn[i]; }
    }
}

// correction term for one (d, row): sum_n pw[n] * Crow[n] * H[n,d]
__device__ __forceinline__ float corr_term(int d, float cd, float Av0, float st,
                                           const float* __restrict__ Alog,
                                           const float* Crow,
                                           const float* __restrict__ Hcol) {
    float s0 = 0.f, s1 = 0.f, s2 = 0.f, s3 = 0.f;
    if (st != 0.f) {
        f32x4 p0, p1, p2, p3;
        pow4(__expf(cd * Av0), p0, p1, p2, p3);
        float pw[16];
        *(f32x4*)&pw[0] = p0; *(f32x4*)&pw[4] = p1;
        *(f32x4*)&pw[8] = p2; *(f32x4*)&pw[12] = p3;
#pragma unroll
        for (int k = 0; k < 4; ++k) {
            s0 = fmaf(pw[k],      Crow[k]      * Hcol[(size_t)k * DI],        s0);
            s1 = fmaf(pw[4 + k],  Crow[4 + k]  * Hcol[(size_t)(4 + k) * DI],  s1);
            s2 = fmaf(pw[8 + k],  Crow[8 + k]  * Hcol[(size_t)(8 + k) * DI],  s2);
            s3 = fmaf(pw[12 + k], Crow[12 + k] * Hcol[(size_t)(12 + k) * DI], s3);
        }
    } else {
#pragma unroll
        for (int k = 0; k < 4; ++k) {
            s0 = fmaf(__expf(cd * -__expf(Alog[(size_t)d * NS + k])),
                      Crow[k] * Hcol[(size_t)k * DI], s0);
            s1 = fmaf(__expf(cd * -__expf(Alog[(size_t)d * NS + 4 + k])),
                      Crow[4 + k] * Hcol[(size_t)(4 + k) * DI], s1);
            s2 = fmaf(__expf(cd * -__expf(Alog[(size_t)d * NS + 8 + k])),
                      Crow[8 + k] * Hcol[(size_t)(8 + k) * DI], s2);
            s3 = fmaf(__expf(cd * -__expf(Alog[(size_t)d * NS + 12 + k])),
                      Crow[12 + k] * Hcol[(size_t)(12 + k) * DI], s3);
        }
    }
    return (s0 + s1) + (s2 + s3);
}

// FUSED pass C + combine + rmsnorm: per block = (chunk c, row-quad rp, batch bb).
// Computes corrected y_f (chunk c) and corrected y_b at the flip rows (chunk 63-c),
// g = (y_f + y_b_flip) * silu(z), block-wide RMS per row, writes bf16 g.
// Chunk-0 corrections are naturally zero (H[c=0] = 0 stored by scan_combine).
__global__ void apply_combine(
    const float* __restrict__ UF, const float* __restrict__ UB,
    const float* __restrict__ Zb,
    const float* __restrict__ DTF, const float* __restrict__ DTB,
    const float* __restrict__ dblf, const float* __restrict__ dblb,
    const float* __restrict__ Pf, const float* __restrict__ Pb,
    const float* __restrict__ Av0S, const float* __restrict__ stS,
    const float* __restrict__ Alf, const float* __restrict__ Alb,
    const float* __restrict__ nw,
    short* __restrict__ g) {
    const int c = blockIdx.x;          // fwd chunk 0..63
    const int rp = blockIdx.y;         // row-quad 0..3
    const int bb = blockIdx.z;
    const int cb = NCH - 1 - c;        // bwd chunk of flip rows
    const int tid = threadIdx.x;
    __shared__ float CsF[4][16], CsB[4][16], red[4];
    if (tid < 64) {
        int rr = tid >> 4, n = tid & 15;
        int lf = c * CL + rp * 4 + rr;
        CsF[rr][n] = dblf[(size_t)(bb * L_ + lf) * 96 + 80 + n];
    } else if (tid < 128) {
        int t2 = tid - 64;
        int rr = t2 >> 4, n = t2 & 15;
        int lf = c * CL + rp * 4 + rr;
        CsB[rr][n] = dblb[(size_t)(bb * L_ + (L_ - 1 - lf)) * 96 + 80 + n];
    }
    __syncthreads();
    const size_t hfb = ((size_t)(bb * NCH + c) * NS) * DI;
    const size_t hbb = ((size_t)(bb * NCH + cb) * NS) * DI;
    for (int rr = 0; rr < 4; ++rr) {
        int lf = c * CL + rp * 4 + rr;
        size_t rf = (size_t)bb * L_ + lf;
        size_t rb = (size_t)bb * L_ + (L_ - 1 - lf);
        float gv[8];
        float ss = 0.f;
#pragma unroll
        for (int k = 0; k < 8; ++k) {
            int d = tid + k * 256;
            float cf = corr_term(d, DTF[rf * DI + d], Av0S[d], stS[d], Alf,
                                 &CsF[rr][0], Pf + hfb + d);
            float cbv = corr_term(d, DTB[rb * DI + d], Av0S[DI + d], stS[DI + d], Alb,
                                  &CsB[rr][0], Pb + hbb + d);
            float yf = UF[rf * DI + d] + cf;
            float yb = UB[rb * DI + d] + cbv;
            float zz = Zb[rf * DI + d];
            float gg = (yf + yb) * silu1(zz);
            gv[k] = gg;
            ss += gg * gg;
        }
#pragma unroll
        for (int off = 32; off > 0; off >>= 1) ss += __shfl_down(ss, off, 64);
        if ((tid & 63) == 0) red[tid >> 6] = ss;
        __syncthreads();
        float tot = red[0] + red[1] + red[2] + red[3];
        float rms = rsqrtf(tot / (float)DI + 1e-5f);
#pragma unroll
        for (int k = 0; k < 8; ++k) {
            int d = tid + k * 256;
            g[rf * DI + d] = f2b(gv[k] * rms * nw[d]);
        }
        __syncthreads();
    }
}

extern "C" void kernel_launch(void* const* d_in, const int* in_sizes, int n_in,
                              void* d_out, int out_size, void* d_ws, size_t ws_size,
                              hipStream_t stream) {
    const float* a      = (const float*)d_in[0];
    const float* b      = (const float*)d_in[1];
    const float* Wi     = (const float*)d_in[2];
    const float* conv_w = (const float*)d_in[3];
    const float* conv_b = (const float*)d_in[4];
    const float* Wx     = (const float*)d_in[5];
    const float* Wdt    = (const float*)d_in[6];
    const float* bdt    = (const float*)d_in[7];
    const float* A_log  = (const float*)d_in[8];
    const float* Dvec   = (const float*)d_in[9];
    const float* conv_w_b = (const float*)d_in[10];
    const float* conv_b_b = (const float*)d_in[11];
    const float* Wx_b   = (const float*)d_in[12];
    const float* Wdt_b  = (const float*)d_in[13];
    const float* bdt_b  = (const float*)d_in[14];
    const float* A_log_b = (const float*)d_in[15];
    const float* Dvec_b = (const float*)d_in[16];
    const float* Wo     = (const float*)d_in[17];
    const float* nw     = (const float*)d_in[18];
    float* out = (float*)d_out;

    const int M = B_ * L_;                    // 2048
    const size_t BLD = (size_t)M * DI;        // 4,194,304
    const size_t NDBL = (size_t)M * 96;       // 196,608
    const size_t PSsz = (size_t)NCH * B_ * NS * DI;   // 4,194,304

    float* f = (float*)d_ws;
    float* Zb   = f;  f += BLD;               // z
    float* UF   = f;  f += BLD;               // u_f (y_local fwd)
    float* UB   = f;  f += BLD;               // u_b (y_local bwd)
    float* DTF  = f;  f += BLD;               // dt_f raw -> cd_f
    float* DTB  = f;  f += BLD;               // dt_b raw -> cd_b
    float* dblf = f;  f += NDBL;
    float* dblb = f;  f += NDBL;
    float* Pf   = f;  f += PSsz;              // h_start; aliases split-K 'part'
    float* Sf   = f;  f += PSsz;
    float* Pb   = f;  f += PSsz;
    float* Sb   = f;  f += PSsz;
    float* Av0S = f;  f += (size_t)2 * DI;    // sidecar: Av[0] per (branch, d)
    float* stS  = f;  f += (size_t)2 * DI;    // sidecar: structured flag
    float* part = Pf;                          // 2*NSPLIT*NDBL = 3.15M <= Pf+Sf

    short* s = (short*)f;
    short* abf    = s;  s += (size_t)M * DM;
    short* bbf    = s;  s += (size_t)M * DM;
    short* Wibf   = s;  s += (size_t)2 * DI * DM;
    short* CF     = s;  s += BLD;              // conv out bf16 (fwd)
    short* CB     = s;  s += BLD;              // conv out bf16 (bwd)
    short* Wxbf   = s;  s += (size_t)96 * DI;
    short* Wxbbf  = s;  s += (size_t)96 * DI;
    short* Wdtbf  = s;  s += (size_t)DI * RR;
    short* Wdtbbf = s;  s += (size_t)DI * RR;
    short* dtfbf  = s;  s += (size_t)M * RR;
    short* dtbbf  = s;  s += (size_t)M * RR;
    short* Wobf   = s;  s += (size_t)DM * DI;
    short* gbf    = abf;                       // alias: abf dead after gemm_xz_conv

    dim3 blk(256);

    // 1. all fp32->bf16 casts + Av0/structured sidecar
    cvt_all<<<dim3(10884), blk, 0, stream>>>(a, b, Wi, Wx, Wx_b, Wdt, Wdt_b, Wo,
                                             A_log, A_log_b,
                                             abf, bbf, Wibf, Wxbf, Wxbbf, Wdtbf, Wdtbbf,
                                             Wobf, Av0S, stS);
    // 2. fused xz GEMM + conv + SiLU; bz=0: x_f+z (A shared), bz=1: x_b
    gemm_xz_conv<<<dim3(DI / 64, M / 128, 2), blk, 0, stream>>>(
        abf, bbf, Wibf, UF, UB, Zb, CF, CB,
        conv_w, conv_b, conv_w_b, conv_b_b);
    // 3. batched dbl GEMM split-K (both branches, NSPLIT=8)
    gemm_dbl<<<dim3(1, M / 128, 2 * NSPLIT), blk, 0, stream>>>(CF, CB, Wxbf, Wxbbf, part);
    // 4. batched split-K reduce (both branches)
    reduce_dbl<<<dim3(2 * (int)(NDBL / 256)), blk, 0, stream>>>(part, dblf, dblb, dtfbf, dtbbf);
    // 5. batched dt GEMM (both branches, BM=128)
    gemm_dt<<<dim3(DI / 64, M / 128, 2), blk, 0, stream>>>(dtfbf, dtbbf, Wdtbf, Wdtbbf, DTF, DTB);
    // 6. batched pass A local scan (S only; P recomputed downstream)
    scan_chunk<<<dim3(DI / 256, 4, NCH), blk, 0, stream>>>(
        UF, UB, DTF, DTB, bdt, bdt_b, dblf, dblb, A_log, A_log_b, Dvec, Dvec_b,
        Sf, Sb);
    // 7. batched pass B chunk combine (P from cd, 4-deep prefetch)
    scan_combine<<<dim3(2 * B_ * NS * DI / 256), blk, 0, stream>>>(
        Pf, Sf, Pb, Sb, DTF, DTB, A_log, A_log_b);
    // 8. FUSED correction + combine + rmsnorm -> bf16 g
    apply_combine<<<dim3(NCH, 4, B_), blk, 0, stream>>>(
        UF, UB, Zb, DTF, DTB, dblf, dblb, Pf, Pb, Av0S, stS,
        A_log, A_log_b, nw, gbf);
    // 9. output GEMM
    gemm_out<<<dim3(DM / 64, M / 64), blk, 0, stream>>>(gbf, Wobf, out);
}

// Round 9
// 283.101 us; speedup vs baseline: 3.5480x; 3.5480x over previous
//
#include <hip/hip_runtime.h>
#include <hip/hip_bf16.h>
#include <cmath>

#define B_ 2
#define L_ 1024
#define DM 1024
#define DI 2048
#define NS 16
#define RR 64
#define KC 4
#define NCH 64
#define CL (L_ / NCH)   // 16
#define NSPLIT 8        // dbl GEMM split-K factor

#define VMCNT(N) asm volatile("s_waitcnt vmcnt(" #N ")" ::: "memory")

using frag8 = __attribute__((ext_vector_type(8))) short;   // 8 bf16 (4 VGPRs)
using facc4 = __attribute__((ext_vector_type(4))) float;   // MFMA C/D
using f32x4 = __attribute__((ext_vector_type(4))) float;

struct alignas(8) S4v { short x, y, z, w; };

__device__ __forceinline__ short f2b(float v) {
    __hip_bfloat16 h = __float2bfloat16(v);
    return *(short*)&h;
}

__device__ __forceinline__ float silu1(float x) {
    return x / (1.f + __expf(-x));
}

// ---- LDS granule swizzle (16-B granules within a 1024-B 16-row group) ----
__device__ __forceinline__ int swz(int r, int q) {
    return (r * 4 + (q ^ (r & 3))) ^ (((r >> 2) & 1) << 2);
}
__device__ __forceinline__ void swz_src(int l, int& R, int& C) {
    int rho = l >> 2;
    R = rho ^ ((rho >> 2) & 1);
    C = (l & 3) ^ (R & 3);
}

// pw vectors: p0 = q^(1..4), p1 = q^(5..8), p2 = q^(9..12), p3 = q^(13..16)
__device__ __forceinline__ void pow4(float qv, f32x4& p0, f32x4& p1, f32x4& p2, f32x4& p3) {
    float q2 = qv * qv, q3 = q2 * qv, q4 = q2 * q2;
    p0 = (f32x4){qv, q2, q3, q4};
    f32x4 s4 = {q4, q4, q4, q4};
    p1 = p0 * s4;
    f32x4 s8 = s4 * s4;
    p2 = p0 * s8;
    p3 = p1 * s8;
}

// async global->LDS DMA, 16 B per lane. LDS dest is wave-uniform base + lane*16.
__device__ __forceinline__ void async_ld16(const void* g, void* l) {
    __builtin_amdgcn_global_load_lds(
        (const __attribute__((address_space(1))) unsigned int*)g,
        (__attribute__((address_space(3))) unsigned int*)l, 16, 0, 0);
}

__device__ __forceinline__ void cvt4(const float* __restrict__ src, size_t si,
                                     short* __restrict__ dst, size_t di2) {
    float4 v = *(const float4*)(src + si);
    S4v r = { f2b(v.x), f2b(v.y), f2b(v.z), f2b(v.w) };
    *(S4v*)(dst + di2) = r;
}

// ---- one launch converting ALL fp32 inputs to bf16 (a, b-flipped, weights) ----
__global__ void cvt_all(const float* __restrict__ a, const float* __restrict__ b,
                        const float* __restrict__ Wi,
                        const float* __restrict__ Wx, const float* __restrict__ Wxb2,
                        const float* __restrict__ Wdt, const float* __restrict__ Wdtb2,
                        const float* __restrict__ Wo,
                        short* __restrict__ abf, short* __restrict__ bbf,
                        short* __restrict__ Wibf,
                        short* __restrict__ Wxbf, short* __restrict__ Wxbbf,
                        short* __restrict__ Wdtbf, short* __restrict__ Wdtbbf,
                        short* __restrict__ Wobf) {
    size_t i = ((size_t)blockIdx.x * 256 + threadIdx.x) * 4;
    const size_t S_ab = (size_t)B_ * L_ * DM;
    if (i < S_ab) { cvt4(a, i, abf, i); return; } i -= S_ab;
    if (i < S_ab) {                      // b, flipped along L
        size_t r = i / DM, c = i % DM;
        size_t bb = r / L_, ll = r % L_;
        size_t sr = bb * L_ + (L_ - 1 - ll);
        cvt4(b, sr * DM + c, bbf, i); return;
    } i -= S_ab;
    const size_t S_wi = (size_t)2 * DI * DM;
    if (i < S_wi) { cvt4(Wi, i, Wibf, i); return; } i -= S_wi;
    const size_t S_wx = (size_t)96 * DI;
    if (i < S_wx) { cvt4(Wx, i, Wxbf, i); return; } i -= S_wx;
    if (i < S_wx) { cvt4(Wxb2, i, Wxbbf, i); return; } i -= S_wx;
    const size_t S_wd = (size_t)DI * RR;
    if (i < S_wd) { cvt4(Wdt, i, Wdtbf, i); return; } i -= S_wd;
    if (i < S_wd) { cvt4(Wdtb2, i, Wdtbbf, i); return; } i -= S_wd;
    const size_t S_wo = (size_t)DM * DI;
    if (i < S_wo) cvt4(Wo, i, Wobf, i);
}

// ---- shared MFMA GEMM body: depth-2 pipelined (3 LDS bufs, counted vmcnt) ----
template <int BM>
__device__ __forceinline__ void gemm_body(
    const short* A, int lda, const short* W, int ldw, int wRowOff,
    float* C, int ldc, int K, int m0, int n0) {
    constexpr int MF = BM / 32;
    __shared__ __align__(16) short As[3][BM * 32];
    __shared__ __align__(16) short Ws[3][64 * 32];
    const int tid = threadIdx.x;
    const int lane = tid & 63, wv = tid >> 6;
    const int wm = (wv & 1) * (BM / 2), wn = (wv >> 1) * 32;
    const int q = lane >> 4, mr = lane & 15;
    int sR, sC; swz_src(lane, sR, sC);
    const int sg = swz(mr, q) * 8;

    const short* Ag = A + (size_t)(m0 + wv * 16 + sR) * lda + sC * 8;
    const short* Wg = W + (size_t)(n0 + wRowOff + wv * 16 + sR) * ldw + sC * 8;

    facc4 acc[MF][2];
#pragma unroll
    for (int i = 0; i < MF; ++i)
#pragma unroll
        for (int j = 0; j < 2; ++j) acc[i][j] = (facc4){0.f, 0.f, 0.f, 0.f};

    auto stage = [&](int ks, int b) {
        int k0 = ks * 32;
        async_ld16(Ag + k0, &As[b][wv * 512]);
        if constexpr (BM == 128)
            async_ld16(Ag + (size_t)64 * lda + k0, &As[b][wv * 512 + 2048]);
        async_ld16(Wg + k0, &Ws[b][wv * 512]);
    };

    const int nk = K / 32;
    stage(0, 0);
    if (nk > 1) stage(1, 1);
    int buf = 0;
    for (int it = 0; it < nk; ++it) {
        if (it == nk - 1) VMCNT(0);
        else if (BM == 128) VMCNT(3);
        else VMCNT(2);
        __builtin_amdgcn_s_barrier();
        asm volatile("" ::: "memory");
        if (it + 2 < nk) { int b2 = buf + 2; if (b2 >= 3) b2 -= 3; stage(it + 2, b2); }
        frag8 af[MF], wf[2];
#pragma unroll
        for (int t = 0; t < MF; ++t)
            af[t] = *(const frag8*)&As[buf][(wm + t * 16) * 32 + sg];
#pragma unroll
        for (int j = 0; j < 2; ++j)
            wf[j] = *(const frag8*)&Ws[buf][(wn + j * 16) * 32 + sg];
#pragma unroll
        for (int i = 0; i < MF; ++i)
#pragma unroll
            for (int j = 0; j < 2; ++j)
                acc[i][j] = __builtin_amdgcn_mfma_f32_16x16x32_bf16(af[i], wf[j], acc[i][j], 0, 0, 0);
        buf = (buf == 2) ? 0 : buf + 1;
    }
#pragma unroll
    for (int i = 0; i < MF; ++i)
#pragma unroll
        for (int j = 0; j < 2; ++j) {
            int gn = n0 + wn + j * 16 + mr;
#pragma unroll
            for (int e = 0; e < 4; ++e) {
                int gm = m0 + wm + i * 16 + q * 4 + e;
                C[(size_t)gm * ldc + gn] = acc[i][j][e];
            }
        }
}

// ---- fused xz GEMM + depthwise causal conv(K=4) + SiLU (best-measured 2-buffer form) ----
// bz=0: x_f AND z share the staged A tile (16 MFMA/wave/iter); bz=1: x_b.
__global__ __launch_bounds__(256) void gemm_xz_conv(
    const short* __restrict__ abf, const short* __restrict__ bbf,
    const short* __restrict__ Wibf,
    float* __restrict__ UF, float* __restrict__ UB, float* __restrict__ Z,
    short* __restrict__ CFo, short* __restrict__ CBo,
    const float* __restrict__ cwf, const float* __restrict__ cbf2,
    const float* __restrict__ cwb, const float* __restrict__ cbb2) {
    __shared__ __align__(16) char smem[34816];
    short (*As)[4608]  = (short (*)[4608])smem;             // [2][128*32 + 16*32 halo]
    short (*Wsx)[2048] = (short (*)[2048])(smem + 18432);   // [2][64*32]
    short (*Wsz)[2048] = (short (*)[2048])(smem + 26624);   // [2][64*32]
    float (*Xs)[68] = (float (*)[68])smem;                  // [80][68] overlay

    const int bz = blockIdx.z;
    const bool hasZ = (bz == 0);
    const int tid = threadIdx.x;
    const int lane = tid & 63, wv = tid >> 6;
    const int id = blockIdx.y * gridDim.x + blockIdx.x;   // 0..511
    const int xcd = id & 7, idx = id >> 3;
    const int nt = (xcd & 3) * 8 + (idx & 7);             // n-tile 0..31
    const int mt = (xcd >> 2) * 8 + (idx >> 3);           // m-tile 0..15
    const int m0 = mt * 128, n0 = nt * 64;
    const bool hasHalo = (m0 % L_ != 0);
    const int wm = (wv & 1) * 64, wn = (wv >> 1) * 32;
    const int q = lane >> 4, mr = lane & 15;
    int sR, sC; swz_src(lane, sR, sC);
    const int sg = swz(mr, q) * 8;

    const short* A = bz ? bbf : abf;

    const short* Ag  = A + (size_t)(m0 + wv * 16 + sR) * DM + sC * 8;
    const short* Agh = A + (size_t)(m0 - 16 + sR) * DM + sC * 8;
    const short* Wgx = Wibf + (size_t)(n0 + wv * 16 + sR) * DM + sC * 8;
    const short* Wgz = Wibf + (size_t)(n0 + DI + wv * 16 + sR) * DM + sC * 8;

    facc4 accx[4][2], accz[4][2], hacc[2];
#pragma unroll
    for (int i = 0; i < 4; ++i)
#pragma unroll
        for (int j = 0; j < 2; ++j) {
            accx[i][j] = (facc4){0.f, 0.f, 0.f, 0.f};
            accz[i][j] = (facc4){0.f, 0.f, 0.f, 0.f};
        }
#pragma unroll
    for (int j = 0; j < 2; ++j) hacc[j] = (facc4){0.f, 0.f, 0.f, 0.f};

    async_ld16(Ag, &As[0][wv * 512]);
    async_ld16(Ag + (size_t)64 * DM, &As[0][wv * 512 + 2048]);
    async_ld16(Wgx, &Wsx[0][wv * 512]);
    if (hasZ) async_ld16(Wgz, &Wsz[0][wv * 512]);
    if (hasHalo && wv == 0) async_ld16(Agh, &As[0][4096]);

    const int nk = DM / 32;
    for (int it = 0; it < nk; ++it) {
        const int buf = it & 1;
        __syncthreads();
        if (it + 1 < nk) {
            int k0 = (it + 1) * 32;
            async_ld16(Ag + k0, &As[buf ^ 1][wv * 512]);
            async_ld16(Ag + (size_t)64 * DM + k0, &As[buf ^ 1][wv * 512 + 2048]);
            async_ld16(Wgx + k0, &Wsx[buf ^ 1][wv * 512]);
            if (hasZ) async_ld16(Wgz + k0, &Wsz[buf ^ 1][wv * 512]);
            if (hasHalo && wv == 0) async_ld16(Agh + k0, &As[buf ^ 1][4096]);
        }
        frag8 af[4], wfx[2], wfz[2];
#pragma unroll
        for (int t = 0; t < 4; ++t)
            af[t] = *(const frag8*)&As[buf][(wm + t * 16) * 32 + sg];
#pragma unroll
        for (int j = 0; j < 2; ++j)
            wfx[j] = *(const frag8*)&Wsx[buf][(wn + j * 16) * 32 + sg];
        if (hasZ) {
#pragma unroll
            for (int j = 0; j < 2; ++j)
                wfz[j] = *(const frag8*)&Wsz[buf][(wn + j * 16) * 32 + sg];
        }
        if (hasHalo && wm == 0) {
            frag8 afh = *(const frag8*)&As[buf][4096 + sg];
#pragma unroll
            for (int j = 0; j < 2; ++j)
                hacc[j] = __builtin_amdgcn_mfma_f32_16x16x32_bf16(afh, wfx[j], hacc[j], 0, 0, 0);
        }
#pragma unroll
        for (int i = 0; i < 4; ++i)
#pragma unroll
            for (int j = 0; j < 2; ++j)
                accx[i][j] = __builtin_amdgcn_mfma_f32_16x16x32_bf16(af[i], wfx[j], accx[i][j], 0, 0, 0);
        if (hasZ) {
#pragma unroll
            for (int i = 0; i < 4; ++i)
#pragma unroll
                for (int j = 0; j < 2; ++j)
                    accz[i][j] = __builtin_amdgcn_mfma_f32_16x16x32_bf16(af[i], wfz[j], accz[i][j], 0, 0, 0);
        }
    }

    if (hasZ) {
#pragma unroll
        for (int i = 0; i < 4; ++i)
#pragma unroll
            for (int j = 0; j < 2; ++j) {
                int gn = n0 + wn + j * 16 + mr;
#pragma unroll
                for (int e = 0; e < 4; ++e) {
                    int gm = m0 + wm + i * 16 + q * 4 + e;
                    Z[(size_t)gm * DI + gn] = accz[i][j][e];
                }
            }
    }

    const float* cw = bz ? cwb : cwf;
    const float* cb = bz ? cbb2 : cbf2;
    float* U   = bz ? UB : UF;
    short* Co  = bz ? CBo : CFo;
    const int col = tid & 63;
    const int dcol = n0 + col;
    const int rg = tid >> 6;
    float4 wd = *(const float4*)(cw + (size_t)dcol * KC);
    float bd = cb[dcol];

    __syncthreads();    // all As/Ws reads done before overlay
#pragma unroll
    for (int p = 0; p < 2; ++p) {
        if (p == 0) {
            if ((wv & 1) == 0) {
#pragma unroll
                for (int j = 0; j < 2; ++j) {
#pragma unroll
                    for (int e = 0; e < 4; ++e)
                        Xs[q * 4 + e][wn + j * 16 + mr] = hacc[j][e];
#pragma unroll
                    for (int i = 0; i < 4; ++i)
#pragma unroll
                        for (int e = 0; e < 4; ++e)
                            Xs[16 + i * 16 + q * 4 + e][wn + j * 16 + mr] = accx[i][j][e];
                }
            }
        } else {
            if ((wv & 1) == 0) {
#pragma unroll
                for (int j = 0; j < 2; ++j)
#pragma unroll
                    for (int e = 0; e < 4; ++e)
                        Xs[q * 4 + e][wn + j * 16 + mr] = accx[3][j][e];
            } else {
#pragma unroll
                for (int j = 0; j < 2; ++j)
#pragma unroll
                    for (int i = 0; i < 4; ++i)
#pragma unroll
                        for (int e = 0; e < 4; ++e)
                            Xs[16 + i * 16 + q * 4 + e][wn + j * 16 + mr] = accx[i][j][e];
            }
        }
        __syncthreads();
#pragma unroll
        for (int rr = 0; rr < 16; ++rr) {
            int rl = rg * 16 + rr;
            float x0 = Xs[13 + rl][col];
            float x1 = Xs[14 + rl][col];
            float x2 = Xs[15 + rl][col];
            float x3 = Xs[16 + rl][col];
            float v = bd + x0 * wd.x + x1 * wd.y + x2 * wd.z + x3 * wd.w;
            float s2 = silu1(v);
            size_t go = (size_t)(m0 + p * 64 + rl) * DI + dcol;
            U[go] = s2;
            Co[go] = f2b(s2);
        }
        if (p == 0) __syncthreads();
    }
}

// batched dt GEMM: dt[M,DI] = dtraw[M,64] @ Wdt[DI,64]^T, both branches (BM=128)
__global__ __launch_bounds__(256) void gemm_dt(
    const short* __restrict__ dtf, const short* __restrict__ dtb,
    const short* __restrict__ Wf, const short* __restrict__ Wb,
    float* __restrict__ DTF_, float* __restrict__ DTB_) {
    const int bz = blockIdx.z;
    gemm_body<128>(bz ? dtb : dtf, RR, bz ? Wb : Wf, RR, 0,
                   bz ? DTB_ : DTF_, DI, RR, blockIdx.y * 128, blockIdx.x * 64);
}

// final GEMM: out[M,DM] = g[M,DI] @ Wo[DM,DI]^T
__global__ __launch_bounds__(256) void gemm_out(
    const short* __restrict__ gbf, const short* __restrict__ Wobf,
    float* __restrict__ out) {
    gemm_body<64>(gbf, DI, Wobf, DI, 0, out, DM, DI, blockIdx.y * 64, blockIdx.x * 64);
}

// batched dbl GEMM: part[z][M][96] = C{F,B}[M,kchunk] * Wx{f,b}[96,kchunk]^T
__global__ __launch_bounds__(256) void gemm_dbl(
    const short* __restrict__ CF, const short* __restrict__ CB,
    const short* __restrict__ Wxf, const short* __restrict__ Wxb,
    float* __restrict__ part) {
    __shared__ __align__(16) short As[2][128 * 32];
    __shared__ __align__(16) short Ws[2][96 * 32];
    const int br = blockIdx.z / NSPLIT, zz = blockIdx.z % NSPLIT;
    const short* A = br ? CB : CF;
    const short* W = br ? Wxb : Wxf;
    constexpr int Kchunk = DI / NSPLIT;
    const int tid = threadIdx.x;
    const int lane = tid & 63, wv = tid >> 6;
    const int m0 = blockIdx.y * 128;
    const int kOff = zz * Kchunk;
    const int wm = (wv & 1) * 64, wn = (wv >> 1) * 48;
    const int q = lane >> 4, mr = lane & 15;
    int sR, sC; swz_src(lane, sR, sC);
    const int sg = swz(mr, q) * 8;

    const short* Ag = A + (size_t)(m0 + wv * 16 + sR) * DI + sC * 8 + kOff;
    const short* Wg = W + (size_t)(wv * 16 + sR) * DI + sC * 8 + kOff;

    facc4 acc[4][3];
#pragma unroll
    for (int i = 0; i < 4; ++i)
#pragma unroll
        for (int j = 0; j < 3; ++j) acc[i][j] = (facc4){0.f, 0.f, 0.f, 0.f};

    async_ld16(Ag, &As[0][wv * 512]);
    async_ld16(Ag + (size_t)64 * DI, &As[0][wv * 512 + 2048]);
    async_ld16(Wg, &Ws[0][wv * 512]);
    if (wv < 2) async_ld16(Wg + (size_t)64 * DI, &Ws[0][wv * 512 + 2048]);

    const int nk = Kchunk / 32;
    for (int it = 0; it < nk; ++it) {
        const int buf = it & 1;
        __syncthreads();
        if (it + 1 < nk) {
            int k0 = (it + 1) * 32;
            async_ld16(Ag + k0, &As[buf ^ 1][wv * 512]);
            async_ld16(Ag + (size_t)64 * DI + k0, &As[buf ^ 1][wv * 512 + 2048]);
            async_ld16(Wg + k0, &Ws[buf ^ 1][wv * 512]);
            if (wv < 2) async_ld16(Wg + (size_t)64 * DI + k0, &Ws[buf ^ 1][wv * 512 + 2048]);
        }
        frag8 af[4], wf[3];
#pragma unroll
        for (int t = 0; t < 4; ++t)
            af[t] = *(const frag8*)&As[buf][(wm + t * 16) * 32 + sg];
#pragma unroll
        for (int j = 0; j < 3; ++j)
            wf[j] = *(const frag8*)&Ws[buf][(wn + j * 16) * 32 + sg];
#pragma unroll
        for (int i = 0; i < 4; ++i)
#pragma unroll
            for (int j = 0; j < 3; ++j)
                acc[i][j] = __builtin_amdgcn_mfma_f32_16x16x32_bf16(af[i], wf[j], acc[i][j], 0, 0, 0);
    }
    float* Cz = part + (size_t)blockIdx.z * (B_ * L_) * 96;
#pragma unroll
    for (int i = 0; i < 4; ++i)
#pragma unroll
        for (int j = 0; j < 3; ++j) {
            int gn = wn + j * 16 + mr;
#pragma unroll
            for (int e = 0; e < 4; ++e) {
                int gm = m0 + wm + i * 16 + q * 4 + e;
                Cz[(size_t)gm * 96 + gn] = acc[i][j][e];
            }
        }
}

// batched split-K reduce -> dbl fp32 (both branches); cols 0..63 also -> bf16 dt operand
__global__ void reduce_dbl(const float* __restrict__ part,
                           float* __restrict__ dblf, float* __restrict__ dblb,
                           short* __restrict__ dtf, short* __restrict__ dtb) {
    int idx = blockIdx.x * blockDim.x + threadIdx.x;
    const int T = B_ * L_ * 96;
    int br = 0;
    if (idx >= T) { br = 1; idx -= T; }
    const float* p = part + (size_t)br * NSPLIT * T;
    float s = 0.f;
#pragma unroll
    for (int z = 0; z < NSPLIT; ++z) s += p[(size_t)z * T + idx];
    (br ? dblb : dblf)[idx] = s;
    int row = idx / 96, col = idx % 96;
    if (col < RR) (br ? dtb : dtf)[(size_t)row * RR + col] = f2b(s);
}

__device__ __forceinline__ float softplus2(float raw, float bd2) {
    float x = raw + bd2;
    return (x > 20.f) ? x : log1pf(__expf(x));
}

// Pass A (fused local scan), batched over both branches via blockIdx.y = bb + 2*br.
__global__ void scan_chunk(float* UF, float* UB, float* DTFm, float* DTBm,
                           const float* bdtf, const float* bdtb,
                           const float* dblF, const float* dblB,
                           const float* Alf, const float* Alb,
                           const float* Dvf, const float* Dvb,
                           float* SF, float* SB) {
    __shared__ __align__(16) float BCs[CL][32];
    const int tid = threadIdx.x;
    const int d = blockIdx.x * 256 + tid;
    const int br = blockIdx.y >> 1, bb = blockIdx.y & 1;
    const int c = blockIdx.z;
    const int l0 = c * CL;
    float* __restrict__ u = br ? UB : UF;
    float* __restrict__ dtm = br ? DTBm : DTFm;
    const float* __restrict__ bdt = br ? bdtb : bdtf;
    const float* __restrict__ dbl = br ? dblB : dblF;
    const float* __restrict__ A_log = br ? Alb : Alf;
    const float* __restrict__ Dv = br ? Dvb : Dvf;
    float* __restrict__ Sbuf = br ? SB : SF;
    {
        int e = tid * 2;   // CL*32 = 512 floats
        int row = e >> 5, cc = e & 31;
        *(float2*)&BCs[row][cc] =
            *(const float2*)(dbl + ((size_t)(bb * L_ + l0 + row) * 96 + 64 + cc));
    }
    float Av[NS];
#pragma unroll
    for (int n = 0; n < NS; ++n) Av[n] = -__expf(A_log[d * NS + n]);
    bool structured = true;
#pragma unroll
    for (int n = 1; n < NS; ++n)
        structured = structured &&
            (fabsf(Av[n] - (n + 1) * Av[0]) <= 1e-4f * (n + 1) * fabsf(Av[0]));
    const float bd2 = 2.f * bdt[d];
    const float Dd = Dv[d];
    float cd = 0.f;
    __syncthreads();
    float* __restrict__ up = u + ((size_t)bb * L_ + l0) * DI + d;
    float* __restrict__ dp = dtm + ((size_t)bb * L_ + l0) * DI + d;
    size_t pb = ((size_t)(bb * NCH + c) * NS) * DI + d;

    if (structured) {
        const float Av0 = Av[0];
        f32x4 S4[4];
#pragma unroll
        for (int m = 0; m < 4; ++m) S4[m] = (f32x4){0.f, 0.f, 0.f, 0.f};
        float draw = dp[0], ul = up[0];
        for (int l = 0; l < CL; ++l) {
            float draw_n = 0.f, ul_n = 0.f;
            if (l + 1 < CL) { draw_n = dp[(size_t)(l + 1) * DI]; ul_n = up[(size_t)(l + 1) * DI]; }
            float x = draw + bd2;
            float e = __expf(x);
            float del = (x > 20.f) ? x : __logf(1.f + e);
            cd += del;
            float du = del * ul;
            f32x4 pw0, pw1, pw2, pw3;
            pow4(__expf(del * Av0), pw0, pw1, pw2, pw3);
            const f32x4* BC4 = (const f32x4*)&BCs[l][0];
            f32x4 b0 = BC4[0], b1 = BC4[1], b2 = BC4[2], b3 = BC4[3];
            f32x4 c0 = BC4[4], c1 = BC4[5], c2 = BC4[6], c3 = BC4[7];
            f32x4 du4 = {du, du, du, du};
            S4[0] = pw0 * S4[0] + du4 * b0;
            S4[1] = pw1 * S4[1] + du4 * b1;
            S4[2] = pw2 * S4[2] + du4 * b2;
            S4[3] = pw3 * S4[3] + du4 * b3;
            f32x4 pA = S4[0] * c0 + S4[1] * c1;
            f32x4 pB = S4[2] * c2 + S4[3] * c3;
            f32x4 pv = pA + pB;
            float accv = (pv[0] + pv[1]) + (pv[2] + pv[3]);
            dp[(size_t)l * DI] = cd;
            up[(size_t)l * DI] = accv + ul * Dd;
            draw = draw_n; ul = ul_n;
        }
#pragma unroll
        for (int m = 0; m < 4; ++m)
#pragma unroll
            for (int k2 = 0; k2 < 4; ++k2)
                Sbuf[pb + (size_t)(m * 4 + k2) * DI] = S4[m][k2];
    } else {
        float S[NS];
#pragma unroll
        for (int n = 0; n < NS; ++n) S[n] = 0.f;
        float draw = dp[0], ul = up[0];
        for (int l = 0; l < CL; ++l) {
            float draw_n = 0.f, ul_n = 0.f;
            if (l + 1 < CL) { draw_n = dp[(size_t)(l + 1) * DI]; ul_n = up[(size_t)(l + 1) * DI]; }
            float del = softplus2(draw, bd2);
            cd += del;
            float du = del * ul;
            const float* Brow = &BCs[l][0];
            float pa[4] = {0.f, 0.f, 0.f, 0.f};
#pragma unroll
            for (int j = 0; j < 4; ++j)
#pragma unroll
                for (int k = 0; k < 4; ++k) {
                    int n = j * 4 + k;
                    float dA = __expf(del * Av[n]);
                    S[n] = fmaf(dA, S[n], du * Brow[n]);
                    pa[j] = fmaf(S[n], Brow[16 + n], pa[j]);
                }
            float accv = (pa[0] + pa[1]) + (pa[2] + pa[3]);
            dp[(size_t)l * DI] = cd;
            up[(size_t)l * DI] = accv + ul * Dd;
            draw = draw_n; ul = ul_n;
        }
#pragma unroll
        for (int n = 0; n < NS; ++n)
            Sbuf[pb + (size_t)n * DI] = S[n];
    }
}

// Pass B batched: P recomputed as exp(cd_chunk * Av[n]) from the cumulative-delta matrix.
__global__ void scan_combine(float* __restrict__ PF, const float* __restrict__ SF,
                             float* __restrict__ PB, const float* __restrict__ SB,
                             const float* __restrict__ DTFm, const float* __restrict__ DTBm,
                             const float* __restrict__ Alf, const float* __restrict__ Alb) {
    int g = blockIdx.x * blockDim.x + threadIdx.x;
    const int T = B_ * NS * DI;
    int br = (g >= T);
    int gg = br ? g - T : g;
    float* __restrict__ P = br ? PB : PF;
    const float* __restrict__ S = br ? SB : SF;
    const float* __restrict__ cdm = br ? DTBm : DTFm;
    const float* __restrict__ Alog = br ? Alb : Alf;
    int d = gg % DI;
    int rest = gg / DI;
    int n = rest % NS, bb = rest / NS;
    const float Avn = -__expf(Alog[d * NS + n]);
    const size_t stride = (size_t)NS * DI;
    const size_t cstride = (size_t)CL * DI;
    size_t o = ((size_t)(bb * NCH) * NS + n) * DI + d;
    const float* cp = cdm + ((size_t)bb * L_ + CL - 1) * DI + d;
    float h = 0.f;
    float Cc[4], Sc[4], Cn[4], Sn[4];
#pragma unroll
    for (int i = 0; i < 4; ++i) {
        Cc[i] = cp[(size_t)i * cstride];
        Sc[i] = S[o + (size_t)i * stride];
    }
    for (int c = 0; c < NCH; c += 4) {
        if (c + 4 < NCH) {
#pragma unroll
            for (int i = 0; i < 4; ++i) {
                Cn[i] = cp[(size_t)(c + i + 4) * cstride];
                Sn[i] = S[o + (size_t)(i + 4) * stride];
            }
        }
#pragma unroll
        for (int i = 0; i < 4; ++i) {
            P[o] = h;
            h = fmaf(__expf(Cc[i] * Avn), h, Sc[i]);
            o += stride;
        }
#pragma unroll
        for (int i = 0; i < 4; ++i) { Cc[i] = Cn[i]; Sc[i] = Sn[i]; }
    }
}

// Pass C (correction) batched over both branches; chunk 0 skipped. f32x4 structured path.
// One d per thread: H (chs) hoisted into registers ONCE per block.
__global__ void scan_apply(float* UF, float* UB,
                           const float* DTFm, const float* DTBm,
                           const float* dblF, const float* dblB,
                           const float* Alf, const float* Alb,
                           const float* PF, const float* PB) {
    __shared__ __align__(16) float Cs[CL][16];
    const int tid = threadIdx.x;
    const int d = blockIdx.x * 256 + tid;
    const int br = blockIdx.y >> 1, bb = blockIdx.y & 1;
    const int c = blockIdx.z + 1;
    const int l0 = c * CL;
    float* __restrict__ y = br ? UB : UF;
    const float* __restrict__ cdm = br ? DTBm : DTFm;
    const float* __restrict__ dbl = br ? dblB : dblF;
    const float* __restrict__ A_log = br ? Alb : Alf;
    const float* __restrict__ Hbuf = br ? PB : PF;
    {
        int row = tid >> 4, cc = tid & 15;   // CL*16 = 256 floats
        Cs[row][cc] = dbl[(size_t)(bb * L_ + l0 + row) * 96 + 80 + cc];
    }
    float Av[NS];
#pragma unroll
    for (int n = 0; n < NS; ++n) Av[n] = -__expf(A_log[d * NS + n]);
    bool structured = true;
#pragma unroll
    for (int n = 1; n < NS; ++n)
        structured = structured &&
            (fabsf(Av[n] - (n + 1) * Av[0]) <= 1e-4f * (n + 1) * fabsf(Av[0]));
    size_t pb = ((size_t)(bb * NCH + c) * NS) * DI + d;
    const float* __restrict__ cp = cdm + ((size_t)bb * L_ + l0) * DI + d;
    float* __restrict__ yp = y + ((size_t)bb * L_ + l0) * DI + d;

    if (structured) {
        f32x4 ch4[4];
#pragma unroll
        for (int m = 0; m < 4; ++m)
#pragma unroll
            for (int k2 = 0; k2 < 4; ++k2)
                ch4[m][k2] = Hbuf[pb + (size_t)(m * 4 + k2) * DI];
        __syncthreads();
        const float Av0 = Av[0];
        float cdv = cp[0], yv = yp[0];
        for (int l = 0; l < CL; ++l) {
            float cdn = 0.f, yn = 0.f;
            if (l + 1 < CL) { cdn = cp[(size_t)(l + 1) * DI]; yn = yp[(size_t)(l + 1) * DI]; }
            f32x4 pw0, pw1, pw2, pw3;
            pow4(__expf(cdv * Av0), pw0, pw1, pw2, pw3);
            const f32x4* C4 = (const f32x4*)&Cs[l][0];
            f32x4 pA = pw0 * (C4[0] * ch4[0]) + pw1 * (C4[1] * ch4[1]);
            f32x4 pB = pw2 * (C4[2] * ch4[2]) + pw3 * (C4[3] * ch4[3]);
            f32x4 pv = pA + pB;
            yp[(size_t)l * DI] = yv + (pv[0] + pv[1]) + (pv[2] + pv[3]);
            cdv = cdn; yv = yn;
        }
    } else {
        float chs[NS];
#pragma unroll
        for (int n = 0; n < NS; ++n) chs[n] = Hbuf[pb + (size_t)n * DI];
        __syncthreads();
        float cdv = cp[0], yv = yp[0];
        for (int l = 0; l < CL; ++l) {
            float cdn = 0.f, yn = 0.f;
            if (l + 1 < CL) { cdn = cp[(size_t)(l + 1) * DI]; yn = yp[(size_t)(l + 1) * DI]; }
            const float* Crow = &Cs[l][0];
            float pa[4] = {0.f, 0.f, 0.f, 0.f};
#pragma unroll
            for (int j = 0; j < 4; ++j)
#pragma unroll
                for (int k = 0; k < 4; ++k) {
                    int n = j * 4 + k;
                    pa[j] = fmaf(__expf(cdv * Av[n]), Crow[n] * chs[n], pa[j]);
                }
            yp[(size_t)l * DI] = yv + (pa[0] + pa[1]) + (pa[2] + pa[3]);
            cdv = cdn; yv = yn;
        }
    }
}

// g = (y_f + flip(y_b)) * silu(z); rmsnorm; emit bf16 for the final MFMA GEMM. float4.
__global__ void combine_rms(const float* __restrict__ yf, const float* __restrict__ yb,
                            const float* __restrict__ z,
                            const float* __restrict__ nw,
                            short* __restrict__ g) {
    int row = blockIdx.x;
    int bb = row / L_, l = row % L_;
    int tid = threadIdx.x;
    size_t base = (size_t)row * DI;
    size_t baseb = ((size_t)bb * L_ + (L_ - 1 - l)) * DI;
    float4 gv[2];
    float ss = 0.f;
#pragma unroll
    for (int j = 0; j < 2; ++j) {
        int d = tid * 4 + j * 1024;
        float4 a4 = *(const float4*)(yf + base + d);
        float4 b4 = *(const float4*)(yb + baseb + d);
        float4 z4 = *(const float4*)(z + base + d);
        float4 r;
        r.x = (a4.x + b4.x) * silu1(z4.x);
        r.y = (a4.y + b4.y) * silu1(z4.y);
        r.z = (a4.z + b4.z) * silu1(z4.z);
        r.w = (a4.w + b4.w) * silu1(z4.w);
        gv[j] = r;
        ss += r.x * r.x + r.y * r.y + r.z * r.z + r.w * r.w;
    }
#pragma unroll
    for (int off = 32; off > 0; off >>= 1) ss += __shfl_down(ss, off, 64);
    __shared__ float red[4];
    if ((tid & 63) == 0) red[tid >> 6] = ss;
    __syncthreads();
    float tot = red[0] + red[1] + red[2] + red[3];
    float rms = rsqrtf(tot / (float)DI + 1e-5f);
#pragma unroll
    for (int j = 0; j < 2; ++j) {
        int d = tid * 4 + j * 1024;
        float4 w4 = *(const float4*)(nw + d);
        S4v o = { f2b(gv[j].x * rms * w4.x), f2b(gv[j].y * rms * w4.y),
                  f2b(gv[j].z * rms * w4.z), f2b(gv[j].w * rms * w4.w) };
        *(S4v*)(g + base + d) = o;
    }
}

extern "C" void kernel_launch(void* const* d_in, const int* in_sizes, int n_in,
                              void* d_out, int out_size, void* d_ws, size_t ws_size,
                              hipStream_t stream) {
    const float* a      = (const float*)d_in[0];
    const float* b      = (const float*)d_in[1];
    const float* Wi     = (const float*)d_in[2];
    const float* conv_w = (const float*)d_in[3];
    const float* conv_b = (const float*)d_in[4];
    const float* Wx     = (const float*)d_in[5];
    const float* Wdt    = (const float*)d_in[6];
    const float* bdt    = (const float*)d_in[7];
    const float* A_log  = (const float*)d_in[8];
    const float* Dvec   = (const float*)d_in[9];
    const float* conv_w_b = (const float*)d_in[10];
    const float* conv_b_b = (const float*)d_in[11];
    const float* Wx_b   = (const float*)d_in[12];
    const float* Wdt_b  = (const float*)d_in[13];
    const float* bdt_b  = (const float*)d_in[14];
    const float* A_log_b = (const float*)d_in[15];
    const float* Dvec_b = (const float*)d_in[16];
    const float* Wo     = (const float*)d_in[17];
    const float* nw     = (const float*)d_in[18];
    float* out = (float*)d_out;

    const int M = B_ * L_;                    // 2048
    const size_t BLD = (size_t)M * DI;        // 4,194,304
    const size_t NDBL = (size_t)M * 96;       // 196,608
    const size_t PSsz = (size_t)NCH * B_ * NS * DI;   // 4,194,304

    float* f = (float*)d_ws;
    float* Zb   = f;  f += BLD;               // z
    float* UF   = f;  f += BLD;               // u_f -> y_f
    float* UB   = f;  f += BLD;               // u_b -> y_b
    float* DTF  = f;  f += BLD;               // dt_f raw -> cd_f
    float* DTB  = f;  f += BLD;               // dt_b raw -> cd_b
    float* dblf = f;  f += NDBL;
    float* dblb = f;  f += NDBL;
    float* Pf   = f;  f += PSsz;              // h_start; aliases split-K 'part'
    float* Sf   = f;  f += PSsz;
    float* Pb   = f;  f += PSsz;
    float* Sb   = f;  f += PSsz;
    float* part = Pf;                          // 2*NSPLIT*NDBL = 3.15M <= Pf+Sf

    short* s = (short*)f;
    short* abf    = s;  s += (size_t)M * DM;
    short* bbf    = s;  s += (size_t)M * DM;
    short* Wibf   = s;  s += (size_t)2 * DI * DM;
    short* CF     = s;  s += BLD;              // conv out bf16 (fwd)
    short* CB     = s;  s += BLD;              // conv out bf16 (bwd)
    short* Wxbf   = s;  s += (size_t)96 * DI;
    short* Wxbbf  = s;  s += (size_t)96 * DI;
    short* Wdtbf  = s;  s += (size_t)DI * RR;
    short* Wdtbbf = s;  s += (size_t)DI * RR;
    short* dtfbf  = s;  s += (size_t)M * RR;
    short* dtbbf  = s;  s += (size_t)M * RR;
    short* Wobf   = s;  s += (size_t)DM * DI;
    short* gbf    = abf;                       // alias: abf dead after gemm_xz_conv

    dim3 blk(256);

    // 1. all fp32->bf16 casts, float4-vectorized
    cvt_all<<<dim3(10880), blk, 0, stream>>>(a, b, Wi, Wx, Wx_b, Wdt, Wdt_b, Wo,
                                             abf, bbf, Wibf, Wxbf, Wxbbf, Wdtbf, Wdtbbf, Wobf);
    // 2. fused xz GEMM + conv + SiLU; bz=0: x_f+z (A shared), bz=1: x_b
    gemm_xz_conv<<<dim3(DI / 64, M / 128, 2), blk, 0, stream>>>(
        abf, bbf, Wibf, UF, UB, Zb, CF, CB,
        conv_w, conv_b, conv_w_b, conv_b_b);
    // 3. batched dbl GEMM split-K (both branches, NSPLIT=8)
    gemm_dbl<<<dim3(1, M / 128, 2 * NSPLIT), blk, 0, stream>>>(CF, CB, Wxbf, Wxbbf, part);
    // 4. batched split-K reduce (both branches)
    reduce_dbl<<<dim3(2 * (int)(NDBL / 256)), blk, 0, stream>>>(part, dblf, dblb, dtfbf, dtbbf);
    // 5. batched dt GEMM (both branches, BM=128)
    gemm_dt<<<dim3(DI / 64, M / 128, 2), blk, 0, stream>>>(dtfbf, dtbbf, Wdtbf, Wdtbbf, DTF, DTB);
    // 6. batched pass A local scan (S only; P recomputed downstream)
    scan_chunk<<<dim3(DI / 256, 4, NCH), blk, 0, stream>>>(
        UF, UB, DTF, DTB, bdt, bdt_b, dblf, dblb, A_log, A_log_b, Dvec, Dvec_b,
        Sf, Sb);
    // 7. batched pass B chunk combine (P from cd, 4-deep prefetch)
    scan_combine<<<dim3(2 * B_ * NS * DI / 256), blk, 0, stream>>>(
        Pf, Sf, Pb, Sb, DTF, DTB, A_log, A_log_b);
    // 8. batched pass C correction (H register-hoisted, one d per thread)
    scan_apply<<<dim3(DI / 256, 4, NCH - 1), blk, 0, stream>>>(
        UF, UB, DTF, DTB, dblf, dblb, A_log, A_log_b, Pf, Pb);
    // 9. combine + rmsnorm -> bf16
    combine_rms<<<dim3(M), blk, 0, stream>>>(UF, UB, Zb, nw, gbf);
    // 10. output GEMM
    gemm_out<<<dim3(DM / 64, M / 64), blk, 0, stream>>>(gbf, Wobf, out);
}